// Round 1
// baseline (773.133 us; speedup 1.0000x reference)
//
#include <hip/hip_runtime.h>

// RNN-T (Transducer) forward loss, N=16, T=256, U=128, V=256, blank=V-1.
// Anti-diagonal wavefront: 1 wave per example, 2 columns per lane,
// cross-lane neighbor via __shfl_up (pipelined one iteration ahead),
// 8-deep register prefetch ring for the blank/emit gathers.

#define T_DIM 256
#define U_DIM 128
#define V_DIM 256
#define UV (U_DIM * V_DIM)   // 32768 = 1<<15, so t*UV is a shift
#define NEGF (-1e30f)

__device__ __forceinline__ float lse2(float x, float y) {
    float m = fmaxf(x, y);
    float mn = fminf(x, y);
    // both NEGF -> m + log(2) ~ NEGF (finite, no NaN); one NEGF -> exp(-huge)=0 -> m
    return m + __logf(1.0f + __expf(mn - m));
}

__global__ __launch_bounds__(64, 1) void rnnt_alpha_kernel(
        const float* __restrict__ lp, const int* __restrict__ labels,
        const int* __restrict__ lengths, const int* __restrict__ lab_lens,
        float* __restrict__ out, float inv_n) {
    const int n    = blockIdx.x;
    const int lane = threadIdx.x;
    const int u0   = lane * 2;
    const int u1   = u0 + 1;
    const float* lpn = lp + (size_t)n * (size_t)(T_DIM * UV);

    // label used by column u is labels[u-1]
    const int lbl0 = (u0 >= 1) ? labels[n * (U_DIM - 1) + (u0 - 1)] : 0;
    const int lbl1 = labels[n * (U_DIM - 1) + u0];   // u0 <= 126 always

    const int t_len = lengths[n];
    const int u_len = lab_lens[n];
    const int dstar = (t_len - 1) + u_len;   // in [127, 382] for this problem

    // per-column constant element offsets within lpn (added to t*UV):
    const int cb0 = u0 * V_DIM + (V_DIM - 1);        // blank, col u0
    const int cb1 = u1 * V_DIM + (V_DIM - 1);        // blank, col u1
    const int ce0 = (u0 - 1) * V_DIM + lbl0;         // emit into col u0 (u0>=1 only)
    const int ce1 = u0 * V_DIM + lbl1;               // emit into col u1

    float a0 = (lane == 0) ? 0.0f : NEGF;  // alpha[0,0] at diagonal 0
    float a1 = NEGF;
    float res = NEGF;
    if (dstar == 0 && lane == 0) res = a0; // safety (unreachable for this problem)

    float nb = __shfl_up(a1, 1, 64);       // neighbor a1 from previous lane

    constexpr int PF = 8;
    float bufB0[PF], bufB1[PF], bufE0[PF], bufE1[PF];

    auto issue = [&](int d, int slot) {
        // loads for diagonal d; clamp t for address safety, mask at consume
        int tb0 = d - 1 - u0;   // blank time index for col u0 (t-1)
        int tb1 = d - 1 - u1;
        int te0 = d - u0;       // emit time index for col u0
        int te1 = d - u1;
        int c;
        c = min(max(tb0, 0), T_DIM - 1); bufB0[slot] = lpn[c * UV + cb0];
        c = min(max(tb1, 0), T_DIM - 1); bufB1[slot] = lpn[c * UV + cb1];
        c = min(max(te0, 0), T_DIM - 1); bufE0[slot] = lpn[c * UV + ce0];
        c = min(max(te1, 0), T_DIM - 1); bufE1[slot] = lpn[c * UV + ce1];
    };

#pragma unroll
    for (int j = 0; j < PF; ++j) issue(1 + j, j);

    // iterate diagonals d = 1..384 (padded past 382; extras clamped+masked)
    for (int dd = 1; dd < 385; dd += PF) {
#pragma unroll
        for (int j = 0; j < PF; ++j) {
            const int d = dd + j;           // slot == j since (dd-1) % PF == 0
            const int t0 = d - u0;
            const int t1 = d - u1;
            const bool vb0 = (unsigned)(t0 - 1) < (unsigned)(T_DIM - 1); // t0 in [1,T-1]
            const bool vb1 = (unsigned)(t1 - 1) < (unsigned)(T_DIM - 1);
            const bool ve0 = (u0 >= 1) && ((unsigned)t0 < (unsigned)T_DIM);
            const bool ve1 = ((unsigned)t1 < (unsigned)T_DIM);           // u1 >= 1 always

            const float pa0 = vb0 ? (a0 + bufB0[j]) : NEGF;
            const float pb0 = ve0 ? (nb + bufE0[j]) : NEGF;
            const float na0 = lse2(pa0, pb0);

            const float pa1 = vb1 ? (a1 + bufB1[j]) : NEGF;
            const float pb1 = ve1 ? (a0 + bufE1[j]) : NEGF;  // uses OLD a0
            const float na1 = lse2(pa1, pb1);

            a0 = na0;
            a1 = na1;
            nb = __shfl_up(a1, 1, 64);      // for next iteration (latency hidden)

            issue(d + PF, j);               // refill slot for diagonal d+PF

            if (d == dstar) {               // uniform scalar branch
                if (u_len == u0)      res = na0;
                else if (u_len == u1) res = na1;
            }
        }
    }

    // lane holding column u_len finishes this example
    if (lane == (u_len >> 1)) {
        const float bl = lpn[(t_len - 1) * UV + u_len * V_DIM + (V_DIM - 1)];
        atomicAdd(out, -(res + bl) * inv_n);
    }
}

extern "C" void kernel_launch(void* const* d_in, const int* in_sizes, int n_in,
                              void* d_out, int out_size, void* d_ws, size_t ws_size,
                              hipStream_t stream) {
    const float* lp      = (const float*)d_in[0];
    const int*   labels  = (const int*)d_in[1];
    const int*   lengths = (const int*)d_in[2];
    const int*   lablens = (const int*)d_in[3];
    float* out = (float*)d_out;
    const int N = in_sizes[2];

    hipMemsetAsync(d_out, 0, sizeof(float), stream);
    rnnt_alpha_kernel<<<dim3(N), dim3(64), 0, stream>>>(
        lp, labels, lengths, lablens, out, 1.0f / (float)N);
}

// Round 2
// 671.230 us; speedup vs baseline: 1.1518x; 1.1518x over previous
//
#include <hip/hip_runtime.h>

// RNN-T (Transducer) forward loss, N=16, T=256, U=128, V=256, blank=V-1.
// Two-kernel design:
//   1) rnnt_gather_kernel: full-chip parallel gather of blank/emit log-probs
//      into diagonal-major buffers in d_ws (coalesced writes, scattered reads
//      at full HBM throughput).
//   2) rnnt_diag_kernel: anti-diagonal wavefront recurrence, 1 wave/example,
//      2 columns/lane, coalesced float2 loads from the compact buffers,
//      cross-lane neighbor via pipelined __shfl_up, register prefetch ring.

#define T_DIM 256
#define U_DIM 128
#define V_DIM 256
#define UV (U_DIM * V_DIM)      // 32768 = 1<<15
#define E_ROWS 384              // diagonals e = t+u in [0, 382], padded to 384
#define NEGF (-1e30f)

__device__ __forceinline__ float lse2(float x, float y) {
    float m = fmaxf(x, y);
    float mn = fminf(x, y);
    return m + __logf(1.0f + __expf(mn - m));
}

// Bd[n][e][u]   = log_probs[n, e-u, u, V-1]            (valid when 0 <= e-u < T)
// Ed[n][e][u+1] = log_probs[n, e-u, u, labels[n,u]]    (u < U-1)
__global__ __launch_bounds__(128) void rnnt_gather_kernel(
        const float* __restrict__ lp, const int* __restrict__ labels,
        float* __restrict__ Bd, float* __restrict__ Ed) {
    const int e = blockIdx.x;          // 0..382
    const int n = blockIdx.y;
    const int u = threadIdx.x;         // 0..127
    const int t = e - u;
    if ((unsigned)t >= (unsigned)T_DIM) return;
    const float* cell = lp + ((size_t)n * T_DIM + t) * (size_t)UV + u * V_DIM;
    float* brow = Bd + ((size_t)n * E_ROWS + e) * U_DIM;
    brow[u] = cell[V_DIM - 1];
    if (u < U_DIM - 1) {
        const int lbl = labels[n * (U_DIM - 1) + u];
        float* erow = Ed + ((size_t)n * E_ROWS + e) * U_DIM;
        erow[u + 1] = cell[lbl];
    }
}

__global__ __launch_bounds__(64, 1) void rnnt_diag_kernel(
        const float* __restrict__ lp,
        const float* __restrict__ Bd, const float* __restrict__ Ed,
        const int* __restrict__ lengths, const int* __restrict__ lab_lens,
        float* __restrict__ out, float inv_n) {
    const int n    = blockIdx.x;
    const int lane = threadIdx.x;
    const int u0   = lane * 2;
    const int u1   = u0 + 1;

    const float* Bdn = Bd + (size_t)n * E_ROWS * U_DIM;
    const float* Edn = Ed + (size_t)n * E_ROWS * U_DIM;

    const int t_len = lengths[n];
    const int u_len = lab_lens[n];
    const int dstar = (t_len - 1) + u_len;   // in [127, 382] here

    float a0 = (lane == 0) ? 0.0f : NEGF;    // alpha[0,0] at diagonal 0
    float a1 = NEGF;
    float res = NEGF;
    if (dstar == 0 && lane == 0) res = a0;   // safety (unreachable here)

    float nb = __shfl_up(a1, 1, 64);         // neighbor a1 from previous lane

    constexpr int PF = 8;
    float2 bufB[PF], bufE[PF];

    auto issue = [&](int d, int slot) {
        const int e = min(d - 1, E_ROWS - 1);        // clamp for address safety
        const float2* br = (const float2*)(Bdn + (size_t)e * U_DIM);
        const float2* er = (const float2*)(Edn + (size_t)e * U_DIM);
        bufB[slot] = br[lane];                       // {B(u0), B(u1)}
        bufE[slot] = er[lane];                       // {E(u0), E(u1)}
    };

#pragma unroll
    for (int j = 0; j < PF; ++j) issue(1 + j, j);

    // diagonals d = 1..384 (padded past 382; extras masked to NEG)
    for (int dd = 1; dd < 385; dd += PF) {
#pragma unroll
        for (int j = 0; j < PF; ++j) {
            const int d = dd + j;                    // slot == j
            const int t0 = d - u0;
            const int t1 = d - u1;
            const bool vb0 = (unsigned)(t0 - 1) < (unsigned)(T_DIM - 1); // t0 in [1,T-1]
            const bool vb1 = (unsigned)(t1 - 1) < (unsigned)(T_DIM - 1);
            const bool ve0 = (u0 >= 1) && ((unsigned)t0 < (unsigned)T_DIM);
            const bool ve1 = ((unsigned)t1 < (unsigned)T_DIM);

            const float pa0 = vb0 ? (a0 + bufB[j].x) : NEGF;
            const float pb0 = ve0 ? (nb + bufE[j].x) : NEGF;
            const float na0 = lse2(pa0, pb0);

            const float pa1 = vb1 ? (a1 + bufB[j].y) : NEGF;
            const float pb1 = ve1 ? (a0 + bufE[j].y) : NEGF;  // OLD a0
            const float na1 = lse2(pa1, pb1);

            a0 = na0;
            a1 = na1;
            nb = __shfl_up(a1, 1, 64);               // for next iteration

            issue(d + PF, j);                        // refill slot

            if (d == dstar) {                        // uniform scalar branch
                if (u_len == u0)      res = na0;
                else if (u_len == u1) res = na1;
            }
        }
    }

    if (lane == (u_len >> 1)) {
        const float bl = lp[(size_t)n * T_DIM * UV + (size_t)(t_len - 1) * UV
                            + u_len * V_DIM + (V_DIM - 1)];
        atomicAdd(out, -(res + bl) * inv_n);
    }
}

extern "C" void kernel_launch(void* const* d_in, const int* in_sizes, int n_in,
                              void* d_out, int out_size, void* d_ws, size_t ws_size,
                              hipStream_t stream) {
    const float* lp      = (const float*)d_in[0];
    const int*   labels  = (const int*)d_in[1];
    const int*   lengths = (const int*)d_in[2];
    const int*   lablens = (const int*)d_in[3];
    float* out = (float*)d_out;
    const int N = in_sizes[2];

    float* Bd = (float*)d_ws;                                // N*384*128 floats = 3 MB
    float* Ed = Bd + (size_t)N * E_ROWS * U_DIM;             // another 3 MB

    hipMemsetAsync(d_out, 0, sizeof(float), stream);
    rnnt_gather_kernel<<<dim3(E_ROWS - 1, N), dim3(128), 0, stream>>>(
        lp, labels, Bd, Ed);
    rnnt_diag_kernel<<<dim3(N), dim3(64), 0, stream>>>(
        lp, Bd, Ed, lengths, lablens, out, 1.0f / (float)N);
}